// Round 11
// baseline (1171.057 us; speedup 1.0000x reference)
//
#include <hip/hip_runtime.h>
#include <stdint.h>
#include <math.h>

#define NN 50000
#define NE 800000

typedef __attribute__((ext_vector_type(8))) __bf16 bf16x8;
typedef __attribute__((ext_vector_type(8))) unsigned short u16x8;
typedef __attribute__((ext_vector_type(16))) float f32x16;

// ---------------------------------------------------------------------------
// One-time CSR build: histogram -> exclusive scan -> scatter (src only).
// ---------------------------------------------------------------------------
__global__ void hist_k(const int* __restrict__ dst, int* __restrict__ hist) {
    int e = blockIdx.x * 256 + threadIdx.x;
    if (e < NE) atomicAdd(&hist[dst[e]], 1);
}

// Chunked exclusive scan: 1024 threads x 49-element serial chunks.
__global__ void scan_k(const int* __restrict__ hist, int* __restrict__ row_off) {
    __shared__ int lds[1024];
    const int tid = threadIdx.x;
    constexpr int CH = (NN + 1023) / 1024;   // 49
    const int lo = tid * CH;
    const int hi = (lo + CH < NN) ? lo + CH : NN;

    int s = 0;
    for (int i = lo; i < hi; ++i) s += hist[i];
    lds[tid] = s;
    __syncthreads();
    #pragma unroll
    for (int st = 1; st < 1024; st <<= 1) {
        int add = (tid >= st) ? lds[tid - st] : 0;
        __syncthreads();
        lds[tid] += add;
        __syncthreads();
    }
    int run = lds[tid] - s;   // exclusive prefix of this chunk
    for (int i = lo; i < hi; ++i) { row_off[i] = run; run += hist[i]; }
    if (tid == 1023) row_off[NN] = lds[1023];
}

__global__ void copy_k(const int* __restrict__ a, int* __restrict__ b, int n) {
    int i = blockIdx.x * 256 + threadIdx.x;
    if (i < n) b[i] = a[i];
}

__global__ void scatter_k(const int* __restrict__ src, const int* __restrict__ dst,
                          int* __restrict__ cnt, int* __restrict__ s_src) {
    int e = blockIdx.x * 256 + threadIdx.x;
    if (e < NE) {
        int d = dst[e];
        int p = atomicAdd(&cnt[d], 1);
        s_src[p] = src[e];
    }
}

// ---------------------------------------------------------------------------
// Degree-bucket counting sort (64 bins) -> node order for pairing.
// Order within a bin is nondeterministic; results are exact per-node max,
// so output is deterministic regardless of pairing.
// ---------------------------------------------------------------------------
__global__ void deg_hist_k(const int* __restrict__ row_off, int* __restrict__ bins) {
    int n = blockIdx.x * 256 + threadIdx.x;
    if (n < NN) {
        int d = row_off[n + 1] - row_off[n];
        atomicAdd(&bins[d < 63 ? d : 63], 1);
    }
}

__global__ void bin_scan_k(const int* __restrict__ bins, int* __restrict__ boff) {
    if (threadIdx.x == 0) {
        int s = 0;
        for (int i = 0; i < 64; ++i) { boff[i] = s; s += bins[i]; }
    }
}

__global__ void order_k(const int* __restrict__ row_off, const int* __restrict__ boff,
                        int* __restrict__ bcnt, int* __restrict__ order) {
    int n = blockIdx.x * 256 + threadIdx.x;
    if (n < NN) {
        int d = row_off[n + 1] - row_off[n];
        int b = d < 63 ? d : 63;
        int p = atomicAdd(&bcnt[b], 1);
        order[boff[b] + p] = n;
    }
}

// ---------------------------------------------------------------------------
// Node transform: u = y @ (W1a - W1b) + b1 ; v = y @ W1b   (fp32 VALU)
// ---------------------------------------------------------------------------
template<int CIN, int COUT, bool FIRST>
__global__ void node_transform(const float* __restrict__ xin,
                               const float* __restrict__ ain,
                               const float* __restrict__ b2p,
                               const float* __restrict__ W1,
                               const float* __restrict__ b1,
                               float* __restrict__ U,
                               float* __restrict__ Vv)
{
    __shared__ float ylds[32][CIN];
    const int nbase = blockIdx.x * 32;
    const int tid = threadIdx.x;

    for (int idx = tid; idx < 32 * CIN; idx += COUT) {
        int nn = idx / CIN, k = idx - nn * CIN;
        int n = nbase + nn;
        float val = 0.f;
        if (n < NN) {
            if (FIRST) {
                val = xin[(size_t)n * CIN + k];
            } else {
                float a = ain[(size_t)n * CIN + k];
                val = fmaxf(a + b2p[k], 0.f);   // -inf sentinel -> 0
            }
        }
        ylds[nn][k] = val;
    }
    __syncthreads();

    const int j = tid;
    float ua[32], va[32];
    #pragma unroll
    for (int t = 0; t < 32; ++t) { ua[t] = 0.f; va[t] = 0.f; }

    for (int k4 = 0; k4 < CIN / 4; ++k4) {
        float wd[4], wb[4];
        #pragma unroll
        for (int i = 0; i < 4; ++i) {
            float a = W1[(size_t)(k4 * 4 + i) * COUT + j];
            float b = W1[(size_t)(CIN + k4 * 4 + i) * COUT + j];
            wb[i] = b;
            wd[i] = a - b;
        }
        #pragma unroll
        for (int t = 0; t < 32; ++t) {
            const float4 y4 = *reinterpret_cast<const float4*>(&ylds[t][k4 * 4]);
            ua[t] = fmaf(y4.x, wd[0], ua[t]);
            ua[t] = fmaf(y4.y, wd[1], ua[t]);
            ua[t] = fmaf(y4.z, wd[2], ua[t]);
            ua[t] = fmaf(y4.w, wd[3], ua[t]);
            va[t] = fmaf(y4.x, wb[0], va[t]);
            va[t] = fmaf(y4.y, wb[1], va[t]);
            va[t] = fmaf(y4.z, wb[2], va[t]);
            va[t] = fmaf(y4.w, wb[3], va[t]);
        }
    }

    const float bj = b1[j];
    for (int t = 0; t < 32; ++t) {
        int n = nbase + t;
        if (n < NN) {
            U [(size_t)n * COUT + j] = ua[t] + bj;
            Vv[(size_t)n * COUT + j] = va[t];
        }
    }
}

// ---------------------------------------------------------------------------
// W2 -> 32x32x16 MFMA B-fragment prep (hi/lo bf16 split), ks-major packing:
// frag = ks*NT + nt; lane l holds W2[ks*16 + (l>>5)*8 + m][nt*32 + (l&31)],
// m=0..7, packed at F[(frag*64+lane)*8].
// ---------------------------------------------------------------------------
template<int COUT>
__global__ void w2frag_prep(const float* __restrict__ W2,
                            unsigned short* __restrict__ Fhi,
                            unsigned short* __restrict__ Flo)
{
    constexpr int NT = COUT / 32;
    constexpr int KS = COUT / 16;
    int t = blockIdx.x * 256 + threadIdx.x;
    if (t >= NT * KS * 64) return;
    int frag = t >> 6, lane = t & 63;
    int nt = frag % NT, ks = frag / NT;
    int col = nt * 32 + (lane & 31);
    int k0 = ks * 16 + (lane >> 5) * 8;
    size_t base = (size_t)t * 8;
    #pragma unroll
    for (int m = 0; m < 8; ++m) {
        float w = W2[(size_t)(k0 + m) * COUT + col];
        __bf16 hb = (__bf16)w;
        float hf = (float)hb;
        __bf16 lb = (__bf16)(w - hf);
        Fhi[base + m] = __builtin_bit_cast(unsigned short, hb);
        Flo[base + m] = __builtin_bit_cast(unsigned short, lb);
    }
}

// ---------------------------------------------------------------------------
// 32x32x16 MFMA edge kernel, NODE-PAIRED tiles + V prefetch.
// Wave w handles nodes A=order[2w] (tile rows 0-15) and B=order[2w+1]
// (rows 16-31); degree-sorted pairing makes ceil(degA/16)~=ceil(degB/16)
// -> ~27% fewer tiles than 1-node-per-32-row tiles at Poisson(16) degrees.
// Per-pass: 16 A-edges + 16 B-edges. V loads depth-1 prefetched across the
// rolled ks loop (round-10 lesson: the ks dependency chain is the limiter).
// B hi+lo both from LDS (round-10 lesson: global lo in the chain costs 20%).
// C/D regs 0-7 = rows 0-15 (A), regs 8-15 = rows 16-31 (B) -> separate
// masked maxes, direct stores, no atomics.
// ---------------------------------------------------------------------------
template<int COUT>
__global__ void __launch_bounds__(512, 2) edge_node_mfma(
    const float* __restrict__ U, const float* __restrict__ Vv,
    const int* __restrict__ s_src, const int* __restrict__ row_off,
    const int* __restrict__ order,
    const unsigned short* __restrict__ Fhi, const unsigned short* __restrict__ Flo,
    float* __restrict__ agg)
{
    constexpr int KS = COUT / 16;          // K-steps (8 / 4)
    constexpr int NT = COUT / 32;          // output col tiles (4 / 2)
    constexpr int NFRAG = KS * NT;

    __shared__ __align__(16) unsigned short w2hi[NFRAG * 512];
    __shared__ __align__(16) unsigned short w2lo[NFRAG * 512];
    __shared__ __align__(16) float u_lds[16 * COUT];

    const int tid = threadIdx.x;
    for (int i = tid; i < NFRAG * 64; i += 512) {
        *reinterpret_cast<u16x8*>(&w2hi[i * 8]) =
            *reinterpret_cast<const u16x8*>(&Fhi[(size_t)i * 8]);
        *reinterpret_cast<u16x8*>(&w2lo[i * 8]) =
            *reinterpret_cast<const u16x8*>(&Flo[(size_t)i * 8]);
    }

    const int wave = tid >> 6, lane = tid & 63;
    const int arow = lane & 31;            // tile row (0-15 A, 16-31 B)
    const int ah   = lane >> 5;            // k-chunk within K-step
    const int isB  = arow >> 4;            // 0 = node A, 1 = node B
    const int er   = arow & 15;            // edge slot within node's 16

    const int pw = blockIdx.x * 8 + wave;  // pair index; grid = NN/16 exactly
    const int nA = order[2 * pw];
    const int nB = order[2 * pw + 1];
    const int offA = row_off[nA], degA = row_off[nA + 1] - offA;
    const int offB = row_off[nB], degB = row_off[nB + 1] - offB;
    const int myn   = isB ? nB : nA;
    const int myoff = isB ? offB : offA;
    const int mydeg = isB ? degB : degA;

    // stage both U rows to LDS (broadcast-read later)
    for (int i = lane; i < COUT; i += 64) {
        u_lds[(2 * wave)     * COUT + i] = U[(size_t)nA * COUT + i];
        u_lds[(2 * wave + 1) * COUT + i] = U[(size_t)nB * COUT + i];
    }
    __syncthreads();   // w2 + U ready; no block syncs after this

    const int ubase = (2 * wave + isB) * COUT;
    const int maxdeg = degA > degB ? degA : degB;

    float nmaxA[NT], nmaxB[NT];
    #pragma unroll
    for (int nt = 0; nt < NT; ++nt) { nmaxA[nt] = -INFINITY; nmaxB[nt] = -INFINITY; }

    for (int pb = 0; pb < maxdeg; pb += 16) {
        const bool valid = (pb + er) < mydeg;
        const int sv = valid ? s_src[myoff + pb + er] : 0;
        const float* vrow = &Vv[(size_t)sv * COUT];

        f32x16 acc[NT];
        #pragma unroll
        for (int nt = 0; nt < NT; ++nt)
            #pragma unroll
            for (int r = 0; r < 16; ++r) acc[nt][r] = 0.f;

        // depth-1 prefetched V chunks across the rolled ks loop
        float4 vaC = *reinterpret_cast<const float4*>(vrow + ah * 8);
        float4 vbC = *reinterpret_cast<const float4*>(vrow + ah * 8 + 4);

        #pragma unroll 1
        for (int ks = 0; ks < KS; ++ks) {
            float4 vaN, vbN;
            if (ks + 1 < KS) {
                const float* vp = vrow + (ks + 1) * 16 + ah * 8;
                vaN = *reinterpret_cast<const float4*>(vp);
                vbN = *reinterpret_cast<const float4*>(vp + 4);
            }

            const int kof = ks * 16 + ah * 8;
            const float4 ua4 = *reinterpret_cast<const float4*>(&u_lds[ubase + kof]);
            const float4 ub4 = *reinterpret_cast<const float4*>(&u_lds[ubase + kof + 4]);

            const float s0 = fmaxf(ua4.x + vaC.x, 0.f);
            const float s1 = fmaxf(ua4.y + vaC.y, 0.f);
            const float s2 = fmaxf(ua4.z + vaC.z, 0.f);
            const float s3 = fmaxf(ua4.w + vaC.w, 0.f);
            const float s4 = fmaxf(ub4.x + vbC.x, 0.f);
            const float s5 = fmaxf(ub4.y + vbC.y, 0.f);
            const float s6 = fmaxf(ub4.z + vbC.z, 0.f);
            const float s7 = fmaxf(ub4.w + vbC.w, 0.f);

            bf16x8 ahi, alo;
            {
                __bf16 h;
                h = (__bf16)s0; ahi[0] = h; alo[0] = (__bf16)(s0 - (float)h);
                h = (__bf16)s1; ahi[1] = h; alo[1] = (__bf16)(s1 - (float)h);
                h = (__bf16)s2; ahi[2] = h; alo[2] = (__bf16)(s2 - (float)h);
                h = (__bf16)s3; ahi[3] = h; alo[3] = (__bf16)(s3 - (float)h);
                h = (__bf16)s4; ahi[4] = h; alo[4] = (__bf16)(s4 - (float)h);
                h = (__bf16)s5; ahi[5] = h; alo[5] = (__bf16)(s5 - (float)h);
                h = (__bf16)s6; ahi[6] = h; alo[6] = (__bf16)(s6 - (float)h);
                h = (__bf16)s7; ahi[7] = h; alo[7] = (__bf16)(s7 - (float)h);
            }

            const unsigned short* hbase = &w2hi[(size_t)(ks * NT * 64 + lane) * 8];
            const unsigned short* lbase = &w2lo[(size_t)(ks * NT * 64 + lane) * 8];
            #pragma unroll
            for (int nt = 0; nt < NT; ++nt) {
                bf16x8 bhi = __builtin_bit_cast(bf16x8,
                    *reinterpret_cast<const u16x8*>(hbase + (size_t)nt * 512));
                bf16x8 blo = __builtin_bit_cast(bf16x8,
                    *reinterpret_cast<const u16x8*>(lbase + (size_t)nt * 512));
                acc[nt] = __builtin_amdgcn_mfma_f32_32x32x16_bf16(ahi, bhi, acc[nt], 0, 0, 0);
                acc[nt] = __builtin_amdgcn_mfma_f32_32x32x16_bf16(ahi, blo, acc[nt], 0, 0, 0);
                acc[nt] = __builtin_amdgcn_mfma_f32_32x32x16_bf16(alo, bhi, acc[nt], 0, 0, 0);
            }
            vaC = vaN; vbC = vbN;
        }

        // masked max. D row = (r&3) + 8*(r>>2) + 4*ah:
        //   regs 0-7 -> rows 0-15 (node A), regs 8-15 -> rows 16-31 (node B)
        #pragma unroll
        for (int nt = 0; nt < NT; ++nt) {
            float mA = -INFINITY, mB = -INFINITY;
            #pragma unroll
            for (int r = 0; r < 8; ++r) {
                const int rowA = (r & 3) + 8 * (r >> 2) + 4 * ah;     // 0..15
                if (pb + rowA < degA) mA = fmaxf(mA, acc[nt][r]);
            }
            #pragma unroll
            for (int r = 8; r < 16; ++r) {
                const int rowB = (r & 3) + 8 * (r >> 2) + 4 * ah - 16; // 0..15
                if (pb + rowB < degB) mB = fmaxf(mB, acc[nt][r]);
            }
            mA = fmaxf(mA, __shfl_xor(mA, 32, 64));
            mB = fmaxf(mB, __shfl_xor(mB, 32, 64));
            nmaxA[nt] = fmaxf(nmaxA[nt], mA);
            nmaxB[nt] = fmaxf(nmaxB[nt], mB);
        }
    }

    // direct stores; deg==0 leaves -inf sentinel
    if (lane < 32) {
        #pragma unroll
        for (int nt = 0; nt < NT; ++nt) {
            agg[(size_t)nA * COUT + nt * 32 + lane] = nmaxA[nt];
            agg[(size_t)nB * COUT + nt * 32 + lane] = nmaxB[nt];
        }
    }
}

__global__ void finalize_k(const float* __restrict__ agg,
                           const float* __restrict__ b2,
                           float* __restrict__ out) {
    int i = blockIdx.x * 256 + threadIdx.x;
    if (i < NN * 128) {
        float a = agg[i];
        out[i] = (a == -INFINITY) ? 0.f : a + b2[i & 127];
    }
}

// ---------------------------------------------------------------------------
extern "C" void kernel_launch(void* const* d_in, const int* in_sizes, int n_in,
                              void* d_out, int out_size, void* d_ws, size_t ws_size,
                              hipStream_t stream)
{
    const float* x  = (const float*)d_in[0];
    const int*   ei = (const int*)d_in[1];
    const int* src = ei;          // edge_index[0]
    const int* dst = ei + NE;     // edge_index[1]

    const float *W1[4], *B1[4], *W2[4], *B2[4];
    for (int i = 0; i < 4; ++i) {
        W1[i] = (const float*)d_in[2 + 4 * i];
        B1[i] = (const float*)d_in[3 + 4 * i];
        W2[i] = (const float*)d_in[4 + 4 * i];
        B2[i] = (const float*)d_in[5 + 4 * i];
    }

    float* U   = (float*)d_ws;
    float* V   = U   + (size_t)NN * 128;
    float* agg = V   + (size_t)NN * 128;
    int* row_off = (int*)(agg + (size_t)NN * 128);   // NN+16 ints (padded)
    int* cnt     = row_off + (NN + 16);              // NN+16 ints
    int* s_src   = cnt + (NN + 16);                  // NE ints
    int* order   = s_src + NE;                       // NN ints
    int* bins    = order + NN;                       // 64
    int* boff    = bins + 64;                        // 64
    int* bcnt    = boff + 64;                        // 64
    unsigned short* fbase = (unsigned short*)(bcnt + 64);
    unsigned short *FH[4], *FL[4];
    for (int i = 0; i < 4; ++i) {
        FH[i] = fbase + (size_t)i * 32768;
        FL[i] = FH[i] + 16384;
    }

    float* out = (float*)d_out;

    // ---- one-time CSR build + degree-sorted node order ----
    (void)hipMemsetAsync(cnt, 0, (size_t)NN * sizeof(int), stream);
    (void)hipMemsetAsync(bins, 0, 192 * sizeof(int), stream);   // bins+boff+bcnt
    hipLaunchKernelGGL(hist_k, dim3((NE + 255) / 256), dim3(256), 0, stream, dst, cnt);
    hipLaunchKernelGGL(scan_k, dim3(1), dim3(1024), 0, stream, cnt, row_off);
    hipLaunchKernelGGL(copy_k, dim3((NN + 255) / 256), dim3(256), 0, stream, row_off, cnt, NN);
    hipLaunchKernelGGL(scatter_k, dim3((NE + 255) / 256), dim3(256), 0, stream, src, dst, cnt, s_src);
    hipLaunchKernelGGL(deg_hist_k, dim3((NN + 255) / 256), dim3(256), 0, stream, row_off, bins);
    hipLaunchKernelGGL(bin_scan_k, dim3(1), dim3(64), 0, stream, bins, boff);
    hipLaunchKernelGGL(order_k, dim3((NN + 255) / 256), dim3(256), 0, stream, row_off, boff, bcnt, order);

    // ---- W2 fragment prep (hi/lo bf16 split, 32x32 ks-major), all layers ----
    hipLaunchKernelGGL((w2frag_prep<64>),  dim3(2), dim3(256), 0, stream, W2[0], FH[0], FL[0]);
    hipLaunchKernelGGL((w2frag_prep<128>), dim3(8), dim3(256), 0, stream, W2[1], FH[1], FL[1]);
    hipLaunchKernelGGL((w2frag_prep<128>), dim3(8), dim3(256), 0, stream, W2[2], FH[2], FL[2]);
    hipLaunchKernelGGL((w2frag_prep<128>), dim3(8), dim3(256), 0, stream, W2[3], FH[3], FL[3]);

    const int nblkA = (NN + 31) / 32;
    const int nblkE = NN / 16;     // 3125 blocks x 8 waves = 25000 pairs

    // ---- layer 0: 32 -> 64 ----
    hipLaunchKernelGGL((node_transform<32, 64, true>), dim3(nblkA), dim3(64), 0, stream,
                       x, nullptr, nullptr, W1[0], B1[0], U, V);
    hipLaunchKernelGGL((edge_node_mfma<64>), dim3(nblkE), dim3(512), 0, stream,
                       U, V, s_src, row_off, order, FH[0], FL[0], agg);

    // ---- layer 1: 64 -> 128 ----
    hipLaunchKernelGGL((node_transform<64, 128, false>), dim3(nblkA), dim3(128), 0, stream,
                       nullptr, agg, B2[0], W1[1], B1[1], U, V);
    hipLaunchKernelGGL((edge_node_mfma<128>), dim3(nblkE), dim3(512), 0, stream,
                       U, V, s_src, row_off, order, FH[1], FL[1], agg);

    // ---- layer 2: 128 -> 128 ----
    hipLaunchKernelGGL((node_transform<128, 128, false>), dim3(nblkA), dim3(128), 0, stream,
                       nullptr, agg, B2[1], W1[2], B1[2], U, V);
    hipLaunchKernelGGL((edge_node_mfma<128>), dim3(nblkE), dim3(512), 0, stream,
                       U, V, s_src, row_off, order, FH[2], FL[2], agg);

    // ---- layer 3: 128 -> 128 ----
    hipLaunchKernelGGL((node_transform<128, 128, false>), dim3(nblkA), dim3(128), 0, stream,
                       nullptr, agg, B2[2], W1[3], B1[3], U, V);
    hipLaunchKernelGGL((edge_node_mfma<128>), dim3(nblkE), dim3(512), 0, stream,
                       U, V, s_src, row_off, order, FH[3], FL[3], agg);

    // ---- finalize: +b2_3, empty -> 0 ----
    hipLaunchKernelGGL(finalize_k, dim3((NN * 128 + 255) / 256), dim3(256), 0, stream,
                       agg, B2[3], out);
}

// Round 12
// 999.639 us; speedup vs baseline: 1.1715x; 1.1715x over previous
//
#include <hip/hip_runtime.h>
#include <stdint.h>
#include <math.h>

#define NN 50000
#define NE 800000

typedef __attribute__((ext_vector_type(8))) __bf16 bf16x8;
typedef __attribute__((ext_vector_type(8))) unsigned short u16x8;
typedef __attribute__((ext_vector_type(16))) float f32x16;

// ---------------------------------------------------------------------------
// One-time CSR build: histogram -> exclusive scan -> scatter (src only).
// ---------------------------------------------------------------------------
__global__ void hist_k(const int* __restrict__ dst, int* __restrict__ hist) {
    int e = blockIdx.x * 256 + threadIdx.x;
    if (e < NE) atomicAdd(&hist[dst[e]], 1);
}

// Chunked exclusive scan; writes row_off AND the scatter cursor (cnt).
__global__ void scan_k(const int* __restrict__ hist, int* __restrict__ row_off,
                       int* __restrict__ cur) {
    __shared__ int lds[1024];
    const int tid = threadIdx.x;
    constexpr int CH = (NN + 1023) / 1024;   // 49
    const int lo = tid * CH;
    const int hi = (lo + CH < NN) ? lo + CH : NN;

    int s = 0;
    for (int i = lo; i < hi; ++i) s += hist[i];
    lds[tid] = s;
    __syncthreads();
    #pragma unroll
    for (int st = 1; st < 1024; st <<= 1) {
        int add = (tid >= st) ? lds[tid - st] : 0;
        __syncthreads();
        lds[tid] += add;
        __syncthreads();
    }
    int run = lds[tid] - s;   // exclusive prefix of this chunk
    for (int i = lo; i < hi; ++i) {
        int h = hist[i];
        row_off[i] = run;
        cur[i] = run;
        run += h;
    }
    if (tid == 1023) row_off[NN] = lds[1023];
}

__global__ void scatter_k(const int* __restrict__ src, const int* __restrict__ dst,
                          int* __restrict__ cur, int* __restrict__ s_src) {
    int e = blockIdx.x * 256 + threadIdx.x;
    if (e < NE) {
        int d = dst[e];
        int p = atomicAdd(&cur[d], 1);
        s_src[p] = src[e];
    }
}

// ---------------------------------------------------------------------------
// Degree-bucket counting sort (64 bins) -> node order for pairing.
// ---------------------------------------------------------------------------
__global__ void deg_hist_k(const int* __restrict__ row_off, int* __restrict__ bins) {
    int n = blockIdx.x * 256 + threadIdx.x;
    if (n < NN) {
        int d = row_off[n + 1] - row_off[n];
        atomicAdd(&bins[d < 63 ? d : 63], 1);
    }
}

__global__ void bin_scan_k(const int* __restrict__ bins, int* __restrict__ boff) {
    if (threadIdx.x == 0) {
        int s = 0;
        for (int i = 0; i < 64; ++i) { boff[i] = s; s += bins[i]; }
    }
}

__global__ void order_k(const int* __restrict__ row_off, const int* __restrict__ boff,
                        int* __restrict__ bcnt, int* __restrict__ order) {
    int n = blockIdx.x * 256 + threadIdx.x;
    if (n < NN) {
        int d = row_off[n + 1] - row_off[n];
        int b = d < 63 ? d : 63;
        int p = atomicAdd(&bcnt[b], 1);
        order[boff[b] + p] = n;
    }
}

// ---------------------------------------------------------------------------
// W1 -> 32x32x16 MFMA B-fragment prep for the NODE transform.
// Combined B = [CIN x 2COUT]: type 0 cols = W1a - W1b (U), type 1 = W1b (V).
// ks-major: frag = ks*NT + nt; lane l holds B[ks*16+(l>>5)*8+m][nt*32+(l&31)].
// ---------------------------------------------------------------------------
template<int CIN, int COUT>
__global__ void w1frag_prep(const float* __restrict__ W1,
                            unsigned short* __restrict__ FhiU, unsigned short* __restrict__ FloU,
                            unsigned short* __restrict__ FhiV, unsigned short* __restrict__ FloV)
{
    constexpr int KS = CIN / 16, NT = COUT / 32, NFRAG = KS * NT;
    int t = blockIdx.x * 256 + threadIdx.x;
    if (t >= 2 * NFRAG * 64) return;
    int type = t / (NFRAG * 64);
    int t2 = t - type * (NFRAG * 64);
    int frag = t2 >> 6, lane = t2 & 63;
    int nt = frag % NT, ks = frag / NT;
    int col = nt * 32 + (lane & 31);
    int k0 = ks * 16 + (lane >> 5) * 8;
    unsigned short* Fh = type ? FhiV : FhiU;
    unsigned short* Fl = type ? FloV : FloU;
    size_t base = (size_t)t2 * 8;
    #pragma unroll
    for (int m = 0; m < 8; ++m) {
        int k = k0 + m;
        float wb = W1[(size_t)(CIN + k) * COUT + col];
        float w = type ? wb : (W1[(size_t)k * COUT + col] - wb);
        __bf16 hb = (__bf16)w;
        float hf = (float)hb;
        __bf16 lb = (__bf16)(w - hf);
        Fh[base + m] = __builtin_bit_cast(unsigned short, hb);
        Fl[base + m] = __builtin_bit_cast(unsigned short, lb);
    }
}

// ---------------------------------------------------------------------------
// NODE transform via 32x32x16 split MFMA (replaces the LDS-broadcast VALU
// version: that one re-read the whole 16KB y-tile per wave, ~60-80us/layer).
// Block = 256 thr = 4 waves = 4 node-tiles of 32 rows. grid.y = type (0:U,1:V)
// so LDS stays at 2*NFRAG KB. A = 32 consecutive node rows gathered direct
// from x/agg (sequential, cache-friendly), relu+b2 fused into A build, b1
// fused into the U epilogue. Same HW-verified A/B/C layouts as edge kernel.
// ---------------------------------------------------------------------------
template<int CIN, int COUT, bool FIRST>
__global__ void __launch_bounds__(256, 2) node_mfma(
    const float* __restrict__ xin, const float* __restrict__ agg_in,
    const float* __restrict__ b2p,
    const unsigned short* __restrict__ FhiU, const unsigned short* __restrict__ FloU,
    const unsigned short* __restrict__ FhiV, const unsigned short* __restrict__ FloV,
    const float* __restrict__ b1,
    float* __restrict__ U, float* __restrict__ Vv)
{
    constexpr int KS = CIN / 16, NT = COUT / 32, NFRAG = KS * NT;

    __shared__ __align__(16) unsigned short w1hi[NFRAG * 512];
    __shared__ __align__(16) unsigned short w1lo[NFRAG * 512];

    const int type = blockIdx.y;
    const unsigned short* Fh = type ? FhiV : FhiU;
    const unsigned short* Fl = type ? FloV : FloU;

    const int tid = threadIdx.x;
    for (int i = tid; i < NFRAG * 64; i += 256) {
        *reinterpret_cast<u16x8*>(&w1hi[i * 8]) =
            *reinterpret_cast<const u16x8*>(&Fh[(size_t)i * 8]);
        *reinterpret_cast<u16x8*>(&w1lo[i * 8]) =
            *reinterpret_cast<const u16x8*>(&Fl[(size_t)i * 8]);
    }
    __syncthreads();

    const int wave = tid >> 6, lane = tid & 63;
    const int arow = lane & 31, ah = lane >> 5;
    const int tile = blockIdx.x * 4 + wave;
    const int node = tile * 32 + arow;
    const bool vn = node < NN;
    const float vm = vn ? 1.f : 0.f;
    const float* yrow = FIRST ? &xin[(size_t)(vn ? node : 0) * CIN]
                              : &agg_in[(size_t)(vn ? node : 0) * CIN];

    f32x16 acc[NT];
    #pragma unroll
    for (int nt = 0; nt < NT; ++nt)
        #pragma unroll
        for (int r = 0; r < 16; ++r) acc[nt][r] = 0.f;

    #pragma unroll 1
    for (int ks = 0; ks < KS; ++ks) {
        const int kof = ks * 16 + ah * 8;
        const float4 y0 = *reinterpret_cast<const float4*>(yrow + kof);
        const float4 y1 = *reinterpret_cast<const float4*>(yrow + kof + 4);

        float s0, s1, s2, s3, s4, s5, s6, s7;
        if (FIRST) {
            s0 = vm * y0.x; s1 = vm * y0.y; s2 = vm * y0.z; s3 = vm * y0.w;
            s4 = vm * y1.x; s5 = vm * y1.y; s6 = vm * y1.z; s7 = vm * y1.w;
        } else {
            const float4 b20 = *reinterpret_cast<const float4*>(b2p + kof);
            const float4 b21 = *reinterpret_cast<const float4*>(b2p + kof + 4);
            s0 = vm * fmaxf(y0.x + b20.x, 0.f);
            s1 = vm * fmaxf(y0.y + b20.y, 0.f);
            s2 = vm * fmaxf(y0.z + b20.z, 0.f);
            s3 = vm * fmaxf(y0.w + b20.w, 0.f);
            s4 = vm * fmaxf(y1.x + b21.x, 0.f);
            s5 = vm * fmaxf(y1.y + b21.y, 0.f);
            s6 = vm * fmaxf(y1.z + b21.z, 0.f);
            s7 = vm * fmaxf(y1.w + b21.w, 0.f);
        }

        bf16x8 ahi, alo;
        {
            __bf16 h;
            h = (__bf16)s0; ahi[0] = h; alo[0] = (__bf16)(s0 - (float)h);
            h = (__bf16)s1; ahi[1] = h; alo[1] = (__bf16)(s1 - (float)h);
            h = (__bf16)s2; ahi[2] = h; alo[2] = (__bf16)(s2 - (float)h);
            h = (__bf16)s3; ahi[3] = h; alo[3] = (__bf16)(s3 - (float)h);
            h = (__bf16)s4; ahi[4] = h; alo[4] = (__bf16)(s4 - (float)h);
            h = (__bf16)s5; ahi[5] = h; alo[5] = (__bf16)(s5 - (float)h);
            h = (__bf16)s6; ahi[6] = h; alo[6] = (__bf16)(s6 - (float)h);
            h = (__bf16)s7; ahi[7] = h; alo[7] = (__bf16)(s7 - (float)h);
        }

        const unsigned short* hbase = &w1hi[(size_t)(ks * NT * 64 + lane) * 8];
        const unsigned short* lbase = &w1lo[(size_t)(ks * NT * 64 + lane) * 8];
        #pragma unroll
        for (int nt = 0; nt < NT; ++nt) {
            bf16x8 bhi = __builtin_bit_cast(bf16x8,
                *reinterpret_cast<const u16x8*>(hbase + (size_t)nt * 512));
            bf16x8 blo = __builtin_bit_cast(bf16x8,
                *reinterpret_cast<const u16x8*>(lbase + (size_t)nt * 512));
            acc[nt] = __builtin_amdgcn_mfma_f32_32x32x16_bf16(ahi, bhi, acc[nt], 0, 0, 0);
            acc[nt] = __builtin_amdgcn_mfma_f32_32x32x16_bf16(ahi, blo, acc[nt], 0, 0, 0);
            acc[nt] = __builtin_amdgcn_mfma_f32_32x32x16_bf16(alo, bhi, acc[nt], 0, 0, 0);
        }
    }

    // epilogue: D row = (r&3)+8*(r>>2)+4*ah (node within tile), col = nt*32+(lane&31)
    float* outp = type ? Vv : U;
    #pragma unroll
    for (int nt = 0; nt < NT; ++nt) {
        const float bb = (type == 0) ? b1[nt * 32 + (lane & 31)] : 0.f;
        #pragma unroll
        for (int r = 0; r < 16; ++r) {
            const int row = (r & 3) + 8 * (r >> 2) + 4 * ah;
            const int nr = tile * 32 + row;
            if (nr < NN)
                outp[(size_t)nr * COUT + nt * 32 + (lane & 31)] = acc[nt][r] + bb;
        }
    }
}

// ---------------------------------------------------------------------------
// W2 -> 32x32x16 MFMA B-fragment prep (hi/lo bf16 split), ks-major packing.
// ---------------------------------------------------------------------------
template<int COUT>
__global__ void w2frag_prep(const float* __restrict__ W2,
                            unsigned short* __restrict__ Fhi,
                            unsigned short* __restrict__ Flo)
{
    constexpr int NT = COUT / 32;
    constexpr int KS = COUT / 16;
    int t = blockIdx.x * 256 + threadIdx.x;
    if (t >= NT * KS * 64) return;
    int frag = t >> 6, lane = t & 63;
    int nt = frag % NT, ks = frag / NT;
    int col = nt * 32 + (lane & 31);
    int k0 = ks * 16 + (lane >> 5) * 8;
    size_t base = (size_t)t * 8;
    #pragma unroll
    for (int m = 0; m < 8; ++m) {
        float w = W2[(size_t)(k0 + m) * COUT + col];
        __bf16 hb = (__bf16)w;
        float hf = (float)hb;
        __bf16 lb = (__bf16)(w - hf);
        Fhi[base + m] = __builtin_bit_cast(unsigned short, hb);
        Flo[base + m] = __builtin_bit_cast(unsigned short, lb);
    }
}

// ---------------------------------------------------------------------------
// 32x32x16 MFMA edge kernel, NODE-PAIRED tiles + V prefetch (round 11, kept).
// ---------------------------------------------------------------------------
template<int COUT>
__global__ void __launch_bounds__(512, 2) edge_node_mfma(
    const float* __restrict__ U, const float* __restrict__ Vv,
    const int* __restrict__ s_src, const int* __restrict__ row_off,
    const int* __restrict__ order,
    const unsigned short* __restrict__ Fhi, const unsigned short* __restrict__ Flo,
    float* __restrict__ agg)
{
    constexpr int KS = COUT / 16;
    constexpr int NT = COUT / 32;
    constexpr int NFRAG = KS * NT;

    __shared__ __align__(16) unsigned short w2hi[NFRAG * 512];
    __shared__ __align__(16) unsigned short w2lo[NFRAG * 512];
    __shared__ __align__(16) float u_lds[16 * COUT];

    const int tid = threadIdx.x;
    for (int i = tid; i < NFRAG * 64; i += 512) {
        *reinterpret_cast<u16x8*>(&w2hi[i * 8]) =
            *reinterpret_cast<const u16x8*>(&Fhi[(size_t)i * 8]);
        *reinterpret_cast<u16x8*>(&w2lo[i * 8]) =
            *reinterpret_cast<const u16x8*>(&Flo[(size_t)i * 8]);
    }

    const int wave = tid >> 6, lane = tid & 63;
    const int arow = lane & 31;
    const int ah   = lane >> 5;
    const int isB  = arow >> 4;
    const int er   = arow & 15;

    const int pw = blockIdx.x * 8 + wave;
    const int nA = order[2 * pw];
    const int nB = order[2 * pw + 1];
    const int offA = row_off[nA], degA = row_off[nA + 1] - offA;
    const int offB = row_off[nB], degB = row_off[nB + 1] - offB;
    const int myoff = isB ? offB : offA;
    const int mydeg = isB ? degB : degA;

    for (int i = lane; i < COUT; i += 64) {
        u_lds[(2 * wave)     * COUT + i] = U[(size_t)nA * COUT + i];
        u_lds[(2 * wave + 1) * COUT + i] = U[(size_t)nB * COUT + i];
    }
    __syncthreads();

    const int ubase = (2 * wave + isB) * COUT;
    const int maxdeg = degA > degB ? degA : degB;

    float nmaxA[NT], nmaxB[NT];
    #pragma unroll
    for (int nt = 0; nt < NT; ++nt) { nmaxA[nt] = -INFINITY; nmaxB[nt] = -INFINITY; }

    for (int pb = 0; pb < maxdeg; pb += 16) {
        const bool valid = (pb + er) < mydeg;
        const int sv = valid ? s_src[myoff + pb + er] : 0;
        const float* vrow = &Vv[(size_t)sv * COUT];

        f32x16 acc[NT];
        #pragma unroll
        for (int nt = 0; nt < NT; ++nt)
            #pragma unroll
            for (int r = 0; r < 16; ++r) acc[nt][r] = 0.f;

        float4 vaC = *reinterpret_cast<const float4*>(vrow + ah * 8);
        float4 vbC = *reinterpret_cast<const float4*>(vrow + ah * 8 + 4);

        #pragma unroll 1
        for (int ks = 0; ks < KS; ++ks) {
            float4 vaN, vbN;
            if (ks + 1 < KS) {
                const float* vp = vrow + (ks + 1) * 16 + ah * 8;
                vaN = *reinterpret_cast<const float4*>(vp);
                vbN = *reinterpret_cast<const float4*>(vp + 4);
            }

            const int kof = ks * 16 + ah * 8;
            const float4 ua4 = *reinterpret_cast<const float4*>(&u_lds[ubase + kof]);
            const float4 ub4 = *reinterpret_cast<const float4*>(&u_lds[ubase + kof + 4]);

            const float s0 = fmaxf(ua4.x + vaC.x, 0.f);
            const float s1 = fmaxf(ua4.y + vaC.y, 0.f);
            const float s2 = fmaxf(ua4.z + vaC.z, 0.f);
            const float s3 = fmaxf(ua4.w + vaC.w, 0.f);
            const float s4 = fmaxf(ub4.x + vbC.x, 0.f);
            const float s5 = fmaxf(ub4.y + vbC.y, 0.f);
            const float s6 = fmaxf(ub4.z + vbC.z, 0.f);
            const float s7 = fmaxf(ub4.w + vbC.w, 0.f);

            bf16x8 ahi, alo;
            {
                __bf16 h;
                h = (__bf16)s0; ahi[0] = h; alo[0] = (__bf16)(s0 - (float)h);
                h = (__bf16)s1; ahi[1] = h; alo[1] = (__bf16)(s1 - (float)h);
                h = (__bf16)s2; ahi[2] = h; alo[2] = (__bf16)(s2 - (float)h);
                h = (__bf16)s3; ahi[3] = h; alo[3] = (__bf16)(s3 - (float)h);
                h = (__bf16)s4; ahi[4] = h; alo[4] = (__bf16)(s4 - (float)h);
                h = (__bf16)s5; ahi[5] = h; alo[5] = (__bf16)(s5 - (float)h);
                h = (__bf16)s6; ahi[6] = h; alo[6] = (__bf16)(s6 - (float)h);
                h = (__bf16)s7; ahi[7] = h; alo[7] = (__bf16)(s7 - (float)h);
            }

            const unsigned short* hbase = &w2hi[(size_t)(ks * NT * 64 + lane) * 8];
            const unsigned short* lbase = &w2lo[(size_t)(ks * NT * 64 + lane) * 8];
            #pragma unroll
            for (int nt = 0; nt < NT; ++nt) {
                bf16x8 bhi = __builtin_bit_cast(bf16x8,
                    *reinterpret_cast<const u16x8*>(hbase + (size_t)nt * 512));
                bf16x8 blo = __builtin_bit_cast(bf16x8,
                    *reinterpret_cast<const u16x8*>(lbase + (size_t)nt * 512));
                acc[nt] = __builtin_amdgcn_mfma_f32_32x32x16_bf16(ahi, bhi, acc[nt], 0, 0, 0);
                acc[nt] = __builtin_amdgcn_mfma_f32_32x32x16_bf16(ahi, blo, acc[nt], 0, 0, 0);
                acc[nt] = __builtin_amdgcn_mfma_f32_32x32x16_bf16(alo, bhi, acc[nt], 0, 0, 0);
            }
            vaC = vaN; vbC = vbN;
        }

        #pragma unroll
        for (int nt = 0; nt < NT; ++nt) {
            float mA = -INFINITY, mB = -INFINITY;
            #pragma unroll
            for (int r = 0; r < 8; ++r) {
                const int rowA = (r & 3) + 8 * (r >> 2) + 4 * ah;
                if (pb + rowA < degA) mA = fmaxf(mA, acc[nt][r]);
            }
            #pragma unroll
            for (int r = 8; r < 16; ++r) {
                const int rowB = (r & 3) + 8 * (r >> 2) + 4 * ah - 16;
                if (pb + rowB < degB) mB = fmaxf(mB, acc[nt][r]);
            }
            mA = fmaxf(mA, __shfl_xor(mA, 32, 64));
            mB = fmaxf(mB, __shfl_xor(mB, 32, 64));
            nmaxA[nt] = fmaxf(nmaxA[nt], mA);
            nmaxB[nt] = fmaxf(nmaxB[nt], mB);
        }
    }

    if (lane < 32) {
        #pragma unroll
        for (int nt = 0; nt < NT; ++nt) {
            agg[(size_t)nA * COUT + nt * 32 + lane] = nmaxA[nt];
            agg[(size_t)nB * COUT + nt * 32 + lane] = nmaxB[nt];
        }
    }
}

__global__ void finalize_k(const float* __restrict__ agg,
                           const float* __restrict__ b2,
                           float* __restrict__ out) {
    int i = blockIdx.x * 256 + threadIdx.x;
    if (i < NN * 128) {
        float a = agg[i];
        out[i] = (a == -INFINITY) ? 0.f : a + b2[i & 127];
    }
}

// ---------------------------------------------------------------------------
extern "C" void kernel_launch(void* const* d_in, const int* in_sizes, int n_in,
                              void* d_out, int out_size, void* d_ws, size_t ws_size,
                              hipStream_t stream)
{
    const float* x  = (const float*)d_in[0];
    const int*   ei = (const int*)d_in[1];
    const int* src = ei;          // edge_index[0]
    const int* dst = ei + NE;     // edge_index[1]

    const float *W1[4], *B1[4], *W2[4], *B2[4];
    for (int i = 0; i < 4; ++i) {
        W1[i] = (const float*)d_in[2 + 4 * i];
        B1[i] = (const float*)d_in[3 + 4 * i];
        W2[i] = (const float*)d_in[4 + 4 * i];
        B2[i] = (const float*)d_in[5 + 4 * i];
    }

    float* U   = (float*)d_ws;
    float* V   = U   + (size_t)NN * 128;
    float* agg = V   + (size_t)NN * 128;
    int* row_off = (int*)(agg + (size_t)NN * 128);   // NN+16 ints
    int* cnt     = row_off + (NN + 16);              // NN+16 ints
    int* s_src   = cnt + (NN + 16);                  // NE ints
    int* order   = s_src + NE;                       // NN ints
    int* bins    = order + NN;                       // 64
    int* boff    = bins + 64;                        // 64
    int* bcnt    = boff + 64;                        // 64
    unsigned short* fbase = (unsigned short*)(bcnt + 64);
    // W2 frags: 4 layers x (hi 16384 + lo 16384)
    unsigned short *FH2[4], *FL2[4];
    for (int i = 0; i < 4; ++i) {
        FH2[i] = fbase + (size_t)i * 32768;
        FL2[i] = FH2[i] + 16384;
    }
    // W1 frags: 4 layers x 4 buffers (UH, UL, VH, VL) x 16384
    unsigned short* f1base = fbase + 4 * 32768;
    unsigned short *UH[4], *UL[4], *VH[4], *VL[4];
    for (int i = 0; i < 4; ++i) {
        UH[i] = f1base + (size_t)i * 65536;
        UL[i] = UH[i] + 16384;
        VH[i] = UL[i] + 16384;
        VL[i] = VH[i] + 16384;
    }

    float* out = (float*)d_out;

    // ---- one-time CSR build + degree-sorted node order ----
    (void)hipMemsetAsync(cnt, 0, (size_t)NN * sizeof(int), stream);
    (void)hipMemsetAsync(bins, 0, 192 * sizeof(int), stream);
    hipLaunchKernelGGL(hist_k, dim3((NE + 255) / 256), dim3(256), 0, stream, dst, cnt);
    hipLaunchKernelGGL(scan_k, dim3(1), dim3(1024), 0, stream, cnt, row_off, cnt);
    hipLaunchKernelGGL(scatter_k, dim3((NE + 255) / 256), dim3(256), 0, stream, src, dst, cnt, s_src);
    hipLaunchKernelGGL(deg_hist_k, dim3((NN + 255) / 256), dim3(256), 0, stream, row_off, bins);
    hipLaunchKernelGGL(bin_scan_k, dim3(1), dim3(64), 0, stream, bins, boff);
    hipLaunchKernelGGL(order_k, dim3((NN + 255) / 256), dim3(256), 0, stream, row_off, boff, bcnt, order);

    // ---- weight fragment prep (all independent of CSR) ----
    hipLaunchKernelGGL((w2frag_prep<64>),  dim3(2), dim3(256), 0, stream, W2[0], FH2[0], FL2[0]);
    hipLaunchKernelGGL((w2frag_prep<128>), dim3(8), dim3(256), 0, stream, W2[1], FH2[1], FL2[1]);
    hipLaunchKernelGGL((w2frag_prep<128>), dim3(8), dim3(256), 0, stream, W2[2], FH2[2], FL2[2]);
    hipLaunchKernelGGL((w2frag_prep<128>), dim3(8), dim3(256), 0, stream, W2[3], FH2[3], FL2[3]);
    hipLaunchKernelGGL((w1frag_prep<32, 64>),   dim3(2),  dim3(256), 0, stream, W1[0], UH[0], UL[0], VH[0], VL[0]);
    hipLaunchKernelGGL((w1frag_prep<64, 128>),  dim3(8),  dim3(256), 0, stream, W1[1], UH[1], UL[1], VH[1], VL[1]);
    hipLaunchKernelGGL((w1frag_prep<128, 128>), dim3(16), dim3(256), 0, stream, W1[2], UH[2], UL[2], VH[2], VL[2]);
    hipLaunchKernelGGL((w1frag_prep<128, 128>), dim3(16), dim3(256), 0, stream, W1[3], UH[3], UL[3], VH[3], VL[3]);

    const int ntiles = (NN + 31) / 32;               // 1563
    const dim3 gN((ntiles + 3) / 4, 2);              // 391 x 2 (type U/V)
    const int nblkE = NN / 16;                       // 3125

    // ---- layer 0: 32 -> 64 ----
    hipLaunchKernelGGL((node_mfma<32, 64, true>), gN, dim3(256), 0, stream,
                       x, nullptr, nullptr, UH[0], UL[0], VH[0], VL[0], B1[0], U, V);
    hipLaunchKernelGGL((edge_node_mfma<64>), dim3(nblkE), dim3(512), 0, stream,
                       U, V, s_src, row_off, order, FH2[0], FL2[0], agg);

    // ---- layer 1: 64 -> 128 ----
    hipLaunchKernelGGL((node_mfma<64, 128, false>), gN, dim3(256), 0, stream,
                       nullptr, agg, B2[0], UH[1], UL[1], VH[1], VL[1], B1[1], U, V);
    hipLaunchKernelGGL((edge_node_mfma<128>), dim3(nblkE), dim3(512), 0, stream,
                       U, V, s_src, row_off, order, FH2[1], FL2[1], agg);

    // ---- layer 2: 128 -> 128 ----
    hipLaunchKernelGGL((node_mfma<128, 128, false>), gN, dim3(256), 0, stream,
                       nullptr, agg, B2[1], UH[2], UL[2], VH[2], VL[2], B1[2], U, V);
    hipLaunchKernelGGL((edge_node_mfma<128>), dim3(nblkE), dim3(512), 0, stream,
                       U, V, s_src, row_off, order, FH2[2], FL2[2], agg);

    // ---- layer 3: 128 -> 128 ----
    hipLaunchKernelGGL((node_mfma<128, 128, false>), gN, dim3(256), 0, stream,
                       nullptr, agg, B2[2], UH[3], UL[3], VH[3], VL[3], B1[3], U, V);
    hipLaunchKernelGGL((edge_node_mfma<128>), dim3(nblkE), dim3(512), 0, stream,
                       U, V, s_src, row_off, order, FH2[3], FL2[3], agg);

    // ---- finalize: +b2_3, empty -> 0 ----
    hipLaunchKernelGGL(finalize_k, dim3((NN * 128 + 255) / 256), dim3(256), 0, stream,
                       agg, B2[3], out);
}